// Round 3
// baseline (160.431 us; speedup 1.0000x reference)
//
#include <hip/hip_runtime.h>
#include <hip/hip_bf16.h>
#include <math.h>

// x: (B=16, S=512, T=64, F=256) fp32.  rows = B*S = 8192, tile = T*F = 16384 floats.
// out[row][f] = sum_t softmax_t( sum_f' x[row][t][f'] * wq[row][f'] ) * x[row][t][f]
// wq[row][f]  = sum_d W[f][d] * x[row][63][d]

#define TT 64
#define FF 256
#define R2 8    // query rows per block in wq kernel

// ---------------- kernel 0: Wt = W^T (tiny, L2-resident afterwards) ----------------
__global__ __launch_bounds__(256) void wt_kernel(const float* __restrict__ W,
                                                 float* __restrict__ Wt) {
    __shared__ float t[32][33];
    const int bx = blockIdx.x & 7;    // d-tile
    const int by = blockIdx.x >> 3;   // f-tile
    const int lx = threadIdx.x & 31;
    const int ly = threadIdx.x >> 5;  // 0..7
#pragma unroll
    for (int i = 0; i < 4; ++i)
        t[ly + i * 8][lx] = W[(size_t)(by * 32 + ly + i * 8) * FF + bx * 32 + lx];
    __syncthreads();
#pragma unroll
    for (int i = 0; i < 4; ++i)
        Wt[(size_t)(bx * 32 + ly + i * 8) * FF + by * 32 + lx] = t[lx][ly + i * 8];
}

// ---------------- kernel 1: wq = W @ q for all rows (VALU-bound, no LDS) ----------------
// thread tid owns output feature f=tid for R2 rows. W reads coalesced via Wt;
// q reads are block-uniform addresses -> scalar loads (SGPR operand into v_fmac).
__global__ __launch_bounds__(256) void wq_kernel(const float* __restrict__ x,
                                                 const float* __restrict__ Wt,
                                                 float* __restrict__ wq) {
    const int tid = threadIdx.x;     // f
    const int r0  = blockIdx.x * R2;

    float acc[R2];
#pragma unroll
    for (int g = 0; g < R2; ++g) acc[g] = 0.f;

    const float* qbase = x + (size_t)r0 * (TT * FF) + (size_t)(TT - 1) * FF;

#pragma unroll 2
    for (int d0 = 0; d0 < FF; d0 += 4) {
        float w0 = Wt[(size_t)(d0 + 0) * FF + tid];
        float w1 = Wt[(size_t)(d0 + 1) * FF + tid];
        float w2 = Wt[(size_t)(d0 + 2) * FF + tid];
        float w3 = Wt[(size_t)(d0 + 3) * FF + tid];
#pragma unroll
        for (int g = 0; g < R2; ++g) {
            float4 qv = *reinterpret_cast<const float4*>(
                qbase + (size_t)g * (TT * FF) + d0);   // uniform address
            acc[g] = fmaf(w0, qv.x, acc[g]);
            acc[g] = fmaf(w1, qv.y, acc[g]);
            acc[g] = fmaf(w2, qv.z, acc[g]);
            acc[g] = fmaf(w3, qv.w, acc[g]);
        }
    }
#pragma unroll
    for (int g = 0; g < R2; ++g)
        wq[(size_t)(r0 + g) * FF + tid] = acc[g];
}

// ---------------- core per-row attention (x read once into registers) ----------------
__device__ __forceinline__ void attn_row(const float* __restrict__ xt,
                                         float4 wqv,
                                         float* __restrict__ out_row,
                                         int tid) {
    const int lane = tid & 63;
    const int w    = tid >> 6;   // wave 0..3, owns t = 16w .. 16w+15

    __shared__ float sc[TT];
    __shared__ float mbuf[4];
    __shared__ float lbuf[4];
    __shared__ float part[4][FF];

    float4 xv[16];
#pragma unroll
    for (int j = 0; j < 16; ++j)
        xv[j] = *reinterpret_cast<const float4*>(
            xt + (size_t)(w * 16 + j) * FF + 4 * lane);

    float p[16];
#pragma unroll
    for (int j = 0; j < 16; ++j)
        p[j] = xv[j].x * wqv.x + xv[j].y * wqv.y + xv[j].z * wqv.z + xv[j].w * wqv.w;

    // fold-reduce: 16 row-sums across 64 lanes in 17 shuffles
    const bool b5 = (lane & 32) != 0;
    const bool b4 = (lane & 16) != 0;
    const bool b3 = (lane & 8) != 0;
    const bool b2 = (lane & 4) != 0;

    float s8[8];
#pragma unroll
    for (int j = 0; j < 8; ++j) {
        float send = b5 ? p[j] : p[j + 8];
        float recv = __shfl_xor(send, 32, 64);
        s8[j] = (b5 ? p[j + 8] : p[j]) + recv;
    }
    float s4[4];
#pragma unroll
    for (int j = 0; j < 4; ++j) {
        float send = b4 ? s8[j] : s8[j + 4];
        float recv = __shfl_xor(send, 16, 64);
        s4[j] = (b4 ? s8[j + 4] : s8[j]) + recv;
    }
    float s2[2];
#pragma unroll
    for (int j = 0; j < 2; ++j) {
        float send = b3 ? s4[j] : s4[j + 2];
        float recv = __shfl_xor(send, 8, 64);
        s2[j] = (b3 ? s4[j + 2] : s4[j]) + recv;
    }
    {
        float send = b2 ? s2[0] : s2[1];
        float recv = __shfl_xor(send, 4, 64);
        s2[0] = (b2 ? s2[1] : s2[0]) + recv;
    }
    float y = s2[0];
    y += __shfl_xor(y, 2, 64);
    y += __shfl_xor(y, 1, 64);          // full score of row (lane>>2)&15

    float mw = y;
    mw = fmaxf(mw, __shfl_xor(mw, 4, 64));
    mw = fmaxf(mw, __shfl_xor(mw, 8, 64));
    mw = fmaxf(mw, __shfl_xor(mw, 16, 64));
    mw = fmaxf(mw, __shfl_xor(mw, 32, 64));

    if ((lane & 3) == 0) sc[w * 16 + (lane >> 2)] = y;
    if (lane == 0) mbuf[w] = mw;
    __syncthreads();

    float m = fmaxf(fmaxf(mbuf[0], mbuf[1]), fmaxf(mbuf[2], mbuf[3]));

    float wt[16];
    float lw = 0.f;
#pragma unroll
    for (int j = 0; j < 16; ++j) {
        wt[j] = __expf(sc[w * 16 + j] - m);
        lw += wt[j];
    }

    float4 acc = make_float4(0.f, 0.f, 0.f, 0.f);
#pragma unroll
    for (int j = 0; j < 16; ++j) {
        acc.x += wt[j] * xv[j].x;
        acc.y += wt[j] * xv[j].y;
        acc.z += wt[j] * xv[j].z;
        acc.w += wt[j] * xv[j].w;
    }
    *reinterpret_cast<float4*>(&part[w][4 * lane]) = acc;
    if (lane == 0) lbuf[w] = lw;
    __syncthreads();

    float l = lbuf[0] + lbuf[1] + lbuf[2] + lbuf[3];
    float v = part[0][tid] + part[1][tid] + part[2][tid] + part[3][tid];
    out_row[tid] = v / l;
}

// ---------------- kernel 2: fused scores + softmax + output (wq precomputed) ----------------
__global__ __launch_bounds__(256) void attn_kernel(const float* __restrict__ x,
                                                   const float* __restrict__ wq,
                                                   float* __restrict__ out) {
    const int row = blockIdx.x;
    const int tid = threadIdx.x;
    const int lane = tid & 63;
    const float* xt = x + (size_t)row * (TT * FF);

    float4 wqv = *reinterpret_cast<const float4*>(wq + (size_t)row * FF + 4 * lane);
    attn_row(xt, wqv, out + (size_t)row * FF, tid);
}

// ---------------- fallback: fully fused (wq computed per block from L2-resident W) ----------------
__global__ __launch_bounds__(256) void fused_kernel(const float* __restrict__ x,
                                                    const float* __restrict__ W,
                                                    float* __restrict__ out) {
    const int row = blockIdx.x;
    const int tid = threadIdx.x;
    const int lane = tid & 63;
    const float* xt = x + (size_t)row * (TT * FF);

    __shared__ float q[FF];
    __shared__ float wqs[FF];
    if (tid < 64) {
        float4 v = *reinterpret_cast<const float4*>(xt + (size_t)(TT - 1) * FF + tid * 4);
        *reinterpret_cast<float4*>(&q[tid * 4]) = v;
    }
    __syncthreads();

    float a = 0.f;
    const float* wrow = W + (size_t)tid * FF;
    for (int d0 = 0; d0 < FF; d0 += 4) {
        float4 wv = *reinterpret_cast<const float4*>(wrow + d0);
        float4 qv = *reinterpret_cast<const float4*>(&q[d0]);
        a += wv.x * qv.x + wv.y * qv.y + wv.z * qv.z + wv.w * qv.w;
    }
    wqs[tid] = a;
    __syncthreads();

    float4 wqv = *reinterpret_cast<const float4*>(&wqs[4 * lane]);
    attn_row(xt, wqv, out + (size_t)row * FF, tid);
}

extern "C" void kernel_launch(void* const* d_in, const int* in_sizes, int n_in,
                              void* d_out, int out_size, void* d_ws, size_t ws_size,
                              hipStream_t stream) {
    (void)n_in; (void)out_size;
    const float* x = (const float*)d_in[0];
    const float* W = (const float*)d_in[1];
    float* out = (float*)d_out;

    const int rows = in_sizes[0] / (TT * FF);   // 8192
    const size_t wq_bytes = (size_t)rows * FF * sizeof(float);
    const size_t wt_bytes = (size_t)FF * FF * sizeof(float);

    if (ws_size >= wq_bytes + wt_bytes) {
        float* wq = (float*)d_ws;
        float* Wt = (float*)((char*)d_ws + wq_bytes);
        wt_kernel<<<64, 256, 0, stream>>>(W, Wt);
        wq_kernel<<<rows / R2, 256, 0, stream>>>(x, Wt, wq);
        attn_kernel<<<rows, 256, 0, stream>>>(x, wq, out);
    } else {
        fused_kernel<<<rows, 256, 0, stream>>>(x, W, out);
    }
}

// Round 4
// 149.324 us; speedup vs baseline: 1.0744x; 1.0744x over previous
//
#include <hip/hip_runtime.h>
#include <hip/hip_bf16.h>
#include <math.h>

// x: (B=16, S=512, T=64, F=256) fp32.  rows = B*S = 8192, tile = T*F = 16384 floats.
// out[row][f] = sum_t softmax_t( sum_f' x[row][t][f'] * wq[row][f'] ) * x[row][t][f]
// wq[row][f]  = sum_d W[f][d] * x[row][63][d]

#define TT 64
#define FF 256
#define QR 8    // query rows per block in wq kernel

// ---------------- kernel 1: wq = W @ q for all rows (R2 version: LDS broadcast) ----------------
__global__ __launch_bounds__(256) void wq_kernel(const float* __restrict__ x,
                                                 const float* __restrict__ W,
                                                 float* __restrict__ wq) {
    __shared__ float q[QR][FF];
    const int tid = threadIdx.x;
    const int r0  = blockIdx.x * QR;

    // stage QR query rows (last timestep of each tile), coalesced float4
    for (int i = tid; i < QR * (FF / 4); i += 256) {
        int g  = i >> 6;        // query row within block
        int d4 = i & 63;        // float4 index
        float4 v = *reinterpret_cast<const float4*>(
            x + (size_t)(r0 + g) * (TT * FF) + (size_t)(TT - 1) * FF + d4 * 4);
        *reinterpret_cast<float4*>(&q[g][d4 * 4]) = v;
    }
    __syncthreads();

    const int f = tid;                       // each thread owns one output feature
    float acc[QR];
#pragma unroll
    for (int g = 0; g < QR; ++g) acc[g] = 0.f;

    const float* wrow = W + (size_t)f * FF;  // W row f, contiguous in d
    for (int d0 = 0; d0 < FF; d0 += 4) {
        float4 wv = *reinterpret_cast<const float4*>(wrow + d0);
#pragma unroll
        for (int g = 0; g < QR; ++g) {
            float4 qv = *reinterpret_cast<const float4*>(&q[g][d0]);  // broadcast, conflict-free
            acc[g] += wv.x * qv.x + wv.y * qv.y + wv.z * qv.z + wv.w * qv.w;
        }
    }
#pragma unroll
    for (int g = 0; g < QR; ++g)
        wq[(size_t)(r0 + g) * FF + f] = acc[g];
}

// ---------------- kernel 2: attention, ONE WAVE PER ROW, online softmax ----------------
// No LDS, no __syncthreads. Wave streams its 64x256 tile in 16 chunks of 4 t-rows,
// double-buffered in registers. Running (m, l, acc) flash-style.
__global__ __launch_bounds__(256) void attn_kernel(const float* __restrict__ x,
                                                   const float* __restrict__ wq,
                                                   float* __restrict__ out) {
    const int tid  = threadIdx.x;
    const int lane = tid & 63;
    const int row  = blockIdx.x * 4 + (tid >> 6);

    const float* xt = x + (size_t)row * (TT * FF) + 4 * lane;   // lane's f-slice
    float4 wqv = *reinterpret_cast<const float4*>(wq + (size_t)row * FF + 4 * lane);

    const bool b5 = (lane & 32) != 0;
    const bool b4 = (lane & 16) != 0;

    float4 A0, A1, A2, A3, B0, B1, B2, B3;
    float4 racc = make_float4(0.f, 0.f, 0.f, 0.f);
    float m_run = -INFINITY, l_run = 0.f;

#define LOADC(Q0, Q1, Q2, Q3, c) do {                                   \
    const float* p_ = xt + (size_t)(c) * 4 * FF;                        \
    Q0 = *reinterpret_cast<const float4*>(p_);                          \
    Q1 = *reinterpret_cast<const float4*>(p_ + FF);                     \
    Q2 = *reinterpret_cast<const float4*>(p_ + 2 * FF);                 \
    Q3 = *reinterpret_cast<const float4*>(p_ + 3 * FF);                 \
} while (0)

#define PROC(Q0, Q1, Q2, Q3) do {                                       \
    float p0 = Q0.x * wqv.x + Q0.y * wqv.y + Q0.z * wqv.z + Q0.w * wqv.w; \
    float p1 = Q1.x * wqv.x + Q1.y * wqv.y + Q1.z * wqv.z + Q1.w * wqv.w; \
    float p2 = Q2.x * wqv.x + Q2.y * wqv.y + Q2.z * wqv.z + Q2.w * wqv.w; \
    float p3 = Q3.x * wqv.x + Q3.y * wqv.y + Q3.z * wqv.z + Q3.w * wqv.w; \
    /* fold bit5: keep rows {0,1} in b5=0 lanes, {2,3} in b5=1 lanes */ \
    float sd0 = b5 ? p0 : p2;                                           \
    float a0  = (b5 ? p2 : p0) + __shfl_xor(sd0, 32, 64);               \
    float sd1 = b5 ? p1 : p3;                                           \
    float a1  = (b5 ? p3 : p1) + __shfl_xor(sd1, 16 * 2, 64);           \
    /* fold bit4: keep row 2*b5+b4 */                                   \
    float sd2 = b4 ? a0 : a1;                                           \
    float y   = (b4 ? a1 : a0) + __shfl_xor(sd2, 16, 64);               \
    /* butterfly bits 0..3 */                                           \
    y += __shfl_xor(y, 8, 64);                                          \
    y += __shfl_xor(y, 4, 64);                                          \
    y += __shfl_xor(y, 2, 64);                                          \
    y += __shfl_xor(y, 1, 64);                                          \
    /* broadcast 4 row-scores from anchor lanes 0/16/32/48 */           \
    float s0 = __shfl(y, 0, 64);                                        \
    float s1 = __shfl(y, 16, 64);                                       \
    float s2 = __shfl(y, 32, 64);                                       \
    float s3 = __shfl(y, 48, 64);                                       \
    float cm = fmaxf(fmaxf(s0, s1), fmaxf(s2, s3));                     \
    if (cm > m_run) {  /* wave-uniform branch */                        \
        float sc_ = __expf(m_run - cm);                                 \
        racc.x *= sc_; racc.y *= sc_; racc.z *= sc_; racc.w *= sc_;     \
        l_run *= sc_;                                                   \
        m_run = cm;                                                     \
    }                                                                   \
    float w0 = __expf(s0 - m_run);                                      \
    float w1 = __expf(s1 - m_run);                                      \
    float w2 = __expf(s2 - m_run);                                      \
    float w3 = __expf(s3 - m_run);                                      \
    l_run += w0 + w1 + w2 + w3;                                         \
    racc.x += w0 * Q0.x + w1 * Q1.x + w2 * Q2.x + w3 * Q3.x;            \
    racc.y += w0 * Q0.y + w1 * Q1.y + w2 * Q2.y + w3 * Q3.y;            \
    racc.z += w0 * Q0.z + w1 * Q1.z + w2 * Q2.z + w3 * Q3.z;            \
    racc.w += w0 * Q0.w + w1 * Q1.w + w2 * Q2.w + w3 * Q3.w;            \
} while (0)

    LOADC(A0, A1, A2, A3, 0);
#pragma unroll
    for (int c = 0; c < 16; c += 2) {
        LOADC(B0, B1, B2, B3, c + 1);
        PROC(A0, A1, A2, A3);
        if (c + 2 < 16) LOADC(A0, A1, A2, A3, c + 2);
        PROC(B0, B1, B2, B3);
    }
#undef LOADC
#undef PROC

    float inv = 1.f / l_run;
    float4 o;
    o.x = racc.x * inv; o.y = racc.y * inv; o.z = racc.z * inv; o.w = racc.w * inv;
    *reinterpret_cast<float4*>(out + (size_t)row * FF + 4 * lane) = o;
}

// ---------------- fallback: fully fused (old structure, only if ws too small) ----------------
__device__ __forceinline__ void attn_row_fb(const float* __restrict__ xt,
                                            float4 wqv,
                                            float* __restrict__ out_row,
                                            int tid) {
    const int lane = tid & 63;
    const int w    = tid >> 6;

    __shared__ float sc[TT];
    __shared__ float part[4][FF];

    float4 xv[16];
#pragma unroll
    for (int j = 0; j < 16; ++j)
        xv[j] = *reinterpret_cast<const float4*>(xt + (size_t)(w * 16 + j) * FF + 4 * lane);

#pragma unroll
    for (int j = 0; j < 16; ++j) {
        float s = xv[j].x * wqv.x + xv[j].y * wqv.y + xv[j].z * wqv.z + xv[j].w * wqv.w;
#pragma unroll
        for (int off = 32; off > 0; off >>= 1)
            s += __shfl_xor(s, off, 64);
        if (lane == 0) sc[w * 16 + j] = s;
    }
    __syncthreads();

    float m = -INFINITY;
#pragma unroll
    for (int t = 0; t < TT; ++t) m = fmaxf(m, sc[t]);
    float l = 0.f;
#pragma unroll
    for (int t = 0; t < TT; ++t) l += __expf(sc[t] - m);

    float4 acc = make_float4(0.f, 0.f, 0.f, 0.f);
#pragma unroll
    for (int j = 0; j < 16; ++j) {
        float wt = __expf(sc[w * 16 + j] - m);
        acc.x += wt * xv[j].x;
        acc.y += wt * xv[j].y;
        acc.z += wt * xv[j].z;
        acc.w += wt * xv[j].w;
    }
    *reinterpret_cast<float4*>(&part[w][4 * lane]) = acc;
    __syncthreads();

    float v = part[0][tid] + part[1][tid] + part[2][tid] + part[3][tid];
    out_row[tid] = v / l;
}

__global__ __launch_bounds__(256) void fused_kernel(const float* __restrict__ x,
                                                    const float* __restrict__ W,
                                                    float* __restrict__ out) {
    const int row = blockIdx.x;
    const int tid = threadIdx.x;
    const int lane = tid & 63;
    const float* xt = x + (size_t)row * (TT * FF);

    __shared__ float q[FF];
    __shared__ float wqs[FF];
    if (tid < 64) {
        float4 v = *reinterpret_cast<const float4*>(xt + (size_t)(TT - 1) * FF + tid * 4);
        *reinterpret_cast<float4*>(&q[tid * 4]) = v;
    }
    __syncthreads();

    float a = 0.f;
    const float* wrow = W + (size_t)tid * FF;
    for (int d0 = 0; d0 < FF; d0 += 4) {
        float4 wv = *reinterpret_cast<const float4*>(wrow + d0);
        float4 qv = *reinterpret_cast<const float4*>(&q[d0]);
        a += wv.x * qv.x + wv.y * qv.y + wv.z * qv.z + wv.w * qv.w;
    }
    wqs[tid] = a;
    __syncthreads();

    float4 wqv = *reinterpret_cast<const float4*>(&wqs[4 * lane]);
    attn_row_fb(xt, wqv, out + (size_t)row * FF, tid);
}

extern "C" void kernel_launch(void* const* d_in, const int* in_sizes, int n_in,
                              void* d_out, int out_size, void* d_ws, size_t ws_size,
                              hipStream_t stream) {
    (void)n_in; (void)out_size;
    const float* x = (const float*)d_in[0];
    const float* W = (const float*)d_in[1];
    float* out = (float*)d_out;

    const int rows = in_sizes[0] / (TT * FF);   // 8192
    const size_t wq_bytes = (size_t)rows * FF * sizeof(float);

    if (ws_size >= wq_bytes) {
        float* wq = (float*)d_ws;
        wq_kernel<<<rows / QR, 256, 0, stream>>>(x, W, wq);
        attn_kernel<<<rows / 4, 256, 0, stream>>>(x, wq, out);
    } else {
        fused_kernel<<<rows, 256, 0, stream>>>(x, W, out);
    }
}